// Round 4
// baseline (682.229 us; speedup 1.0000x reference)
//
#include <hip/hip_runtime.h>

// ---------------- problem constants ----------------
#define NEDGES   100000
#define NODE_DIM 128
#define CTX_DIM  256
#define OUT_DIM  256
#define IN_DIM   384
#define NCOEF    7

// K' = i*8 + slot, slot0=silu, slot1..7=spline c=slot-1
#define BM2      128
#define BK2      32            // 4 x-cols * 8 slots
#define NCH2     96            // IN_DIM / 4
#define THR2     512           // 8 waves
#define TABN     512           // spline payload table entries over t in [0,10]

typedef __bf16 bf16x8 __attribute__((ext_vector_type(8)));
typedef float  f32x4  __attribute__((ext_vector_type(4)));

static __device__ __forceinline__ unsigned short f2bf(float f) {
    unsigned int u = __float_as_uint(f);
    u += 0x7FFFu + ((u >> 16) & 1u);   // RNE
    return (unsigned short)(u >> 16);
}
static __device__ __forceinline__ float bf2f(unsigned short h) {
    return __uint_as_float(((unsigned int)h) << 16);
}
static __device__ __forceinline__ unsigned int pkbf(float a, float b) {
    unsigned int ua = __float_as_uint(a), ub = __float_as_uint(b);
    ua += 0x7FFFu + ((ua >> 16) & 1u);
    ub += 0x7FFFu + ((ub >> 16) & 1u);
    return (ua >> 16) | (ub & 0xFFFF0000u);
}
static __device__ __forceinline__ float silu(float x) {
    return x / (1.0f + __expf(-x));
}
// cardinal cubic B-spline (fallback path)
static __device__ __forceinline__ float n3(float t) {
    float d2 = t - 2.0f;
    float a  = fabsf(d2);
    float p1 = fmaf(fmaf(0.5f, a, -1.0f), d2 * d2, 0.66666667f);
    float dd = fmaxf(2.0f - a, 0.0f);
    float p2 = dd * dd * (dd * (1.0f / 6.0f));
    return a < 1.0f ? p1 : p2;
}

static __device__ __forceinline__ void glds16(const unsigned short* g, unsigned short* l) {
    __builtin_amdgcn_global_load_lds(
        (const __attribute__((address_space(1))) void*)g,
        (__attribute__((address_space(3))) void*)l, 16, 0, 0);
}

// =====================================================================
// W prep: chunk-major [96][256 o][32 k], granule-permuted for LDS banks.
// granule (16B = 8 slots of one (o,i)) at index p = o*4 + (((o>>1)+(i&3))&3)
// =====================================================================
__global__ void prep_w2(const float* __restrict__ base_w,
                        const float* __restrict__ spline_w,
                        const float* __restrict__ spline_s,
                        unsigned short* __restrict__ Wsw)
{
    int o = blockIdx.x;          // 0..255
    int i = threadIdx.x;         // 0..383
    int bi = o * IN_DIM + i;
    float sc = spline_s[bi];
    const float* sw = spline_w + (size_t)bi * NCOEF;
    uint4 v;
    v.x = pkbf(base_w[bi], sw[0] * sc);
    v.y = pkbf(sw[1] * sc, sw[2] * sc);
    v.z = pkbf(sw[3] * sc, sw[4] * sc);
    v.w = pkbf(sw[5] * sc, sw[6] * sc);
    int ch = i >> 2, g8 = i & 3;
    int p  = o * 4 + (((o >> 1) + g8) & 3);
    *(uint4*)(Wsw + (size_t)ch * (OUT_DIM * BK2) + p * 8) = v;
}

// =====================================================================
// build_x: Xbf[e][384] = [bf16(subj) | bf16(obj) | bf16(ctx@ctx_w^T + b)]
// =====================================================================
#define K1STR 72
#define BM   128
__global__ __launch_bounds__(512, 2)
void build_x(const float* __restrict__ node_emb,
             const float* __restrict__ ctx_emb,
             const int*   __restrict__ pair,
             const float* __restrict__ ctx_w,
             const float* __restrict__ ctx_b,
             unsigned short* __restrict__ Xbf)
{
    __shared__ unsigned short sm[2 * 128 * K1STR];
    const int tid    = threadIdx.x;
    const int e_base = blockIdx.x * BM;
    const int wid    = tid >> 6;
    const int lan    = tid & 63;
    const int lrow   = lan & 15;
    const int lquad  = lan >> 4;

    #pragma unroll
    for (int it = 0; it < 16; ++it) {
        int id    = it * 512 + tid;
        int f4    = id & 31;
        int which = (id >> 5) & 1;
        int e     = id >> 6;
        int eg = e_base + e; if (eg >= NEDGES) eg = NEDGES - 1;
        int node = pair[eg * 2 + which];
        float4 v = *(const float4*)(node_emb + (size_t)node * NODE_DIM + f4 * 4);
        *(uint2*)&Xbf[(size_t)eg * IN_DIM + which * NODE_DIM + f4 * 4] =
            make_uint2(pkbf(v.x, v.y), pkbf(v.z, v.w));
    }

    f32x4 acc[4][2];
    #pragma unroll
    for (int a = 0; a < 4; ++a)
        #pragma unroll
        for (int b = 0; b < 2; ++b) { f32x4 z = {0.f,0.f,0.f,0.f}; acc[a][b] = z; }

    const int m0 = (wid & 1) * 64;
    const int n0 = (wid >> 1) * 32;

    for (int kc = 0; kc < 4; ++kc) {
        #pragma unroll
        for (int it = 0; it < 4; ++it) {
            int id = it * 512 + tid;
            int r  = id >> 4;
            int c4 = id & 15;
            int eg = e_base + r; if (eg >= NEDGES) eg = NEDGES - 1;
            float4 v = *(const float4*)(ctx_emb + (size_t)eg * CTX_DIM + kc * 64 + c4 * 4);
            *(uint2*)&sm[r * K1STR + c4 * 4] = make_uint2(pkbf(v.x, v.y), pkbf(v.z, v.w));
            float4 w = *(const float4*)(ctx_w + (size_t)r * CTX_DIM + kc * 64 + c4 * 4);
            *(uint2*)&sm[128 * K1STR + r * K1STR + c4 * 4] = make_uint2(pkbf(w.x, w.y), pkbf(w.z, w.w));
        }
        __syncthreads();
        #pragma unroll
        for (int ks = 0; ks < 2; ++ks) {
            int koff = ks * 32 + lquad * 8;
            bf16x8 af[4], bfr[2];
            #pragma unroll
            for (int mt = 0; mt < 4; ++mt)
                af[mt] = *(const bf16x8*)&sm[(m0 + mt*16 + lrow) * K1STR + koff];
            #pragma unroll
            for (int nt = 0; nt < 2; ++nt)
                bfr[nt] = *(const bf16x8*)&sm[128 * K1STR + (n0 + nt*16 + lrow) * K1STR + koff];
            #pragma unroll
            for (int mt = 0; mt < 4; ++mt)
                #pragma unroll
                for (int nt = 0; nt < 2; ++nt)
                    acc[mt][nt] = __builtin_amdgcn_mfma_f32_16x16x32_bf16(
                        af[mt], bfr[nt], acc[mt][nt], 0, 0, 0);
        }
        __syncthreads();
    }

    #define ESTR 136
    #pragma unroll
    for (int nt = 0; nt < 2; ++nt) {
        int col = n0 + nt * 16 + lrow;
        float cb = ctx_b[col];
        #pragma unroll
        for (int mt = 0; mt < 4; ++mt)
            #pragma unroll
            for (int r = 0; r < 4; ++r) {
                int row = m0 + mt * 16 + lquad * 4 + r;
                sm[row * ESTR + col] = f2bf(acc[mt][nt][r] + cb);
            }
    }
    __syncthreads();
    #pragma unroll
    for (int it = 0; it < 8; ++it) {
        int id = it * 512 + tid;
        int row = id >> 5;
        int g   = id & 31;
        int eg = e_base + row; if (eg >= NEDGES) eg = NEDGES - 1;
        *(uint2*)&Xbf[(size_t)eg * IN_DIM + 256 + g * 4] = *(uint2*)&sm[row * ESTR + g * 4];
    }
}

// =====================================================================
// kan_gemm3: A-fragments generated per-lane in registers from an LDS
// payload table (no A-tile in LDS, no A-barrier). B quad-buffered via
// global_load_lds, ONE barrier per 2 chunks.
// =====================================================================
#define OFF_T  0                               // 512 entries * 8 ush = 4096
#define OFF_B3 (TABN * 8)                      // 4 bufs * 8192 ush
#define LDS3   (TABN * 8 + 4 * 8192)           // 36864 ush = 73728 B

static __device__ __forceinline__ bf16x8 gen_af(unsigned short xh, float hinv, float b0,
                                                const unsigned short* tab) {
    float x = bf2f(xh);
    float t = fmaf(x, hinv, b0);
    int idx = (int)(t * (TABN / 10.0f));
    idx = min(max(idx, 0), TABN - 1);
    uint4 e = *(const uint4*)(tab + idx * 8);
    float sl = silu(x);
    e.x = (e.x & 0xFFFF0000u) | (unsigned)f2bf(sl);   // slot0 = silu
    union { uint4 u; bf16x8 b; } cv; cv.u = e;
    return cv.b;
}

__global__ __launch_bounds__(THR2, 4)
void kan_gemm3(const unsigned short* __restrict__ Wsw,
               const unsigned short* __restrict__ Xbf,
               const float* __restrict__ grid,
               float* __restrict__ out)
{
    __shared__ unsigned short smem[LDS3];
    const int tid    = threadIdx.x;
    const int e_base = blockIdx.x * BM2;
    const int wid    = tid >> 6;
    const int lan    = tid & 63;
    const int lrow   = lan & 15;
    const int lquad  = lan >> 4;
    const int m0     = (wid & 1) * 64;
    const int n0     = (wid >> 1) * 64;

    const float hinv = 1.0f / (grid[1] - grid[0]);
    const float b0   = -grid[0] * hinv;

    // ---- build spline payload table: entry = positioned [0|c0..c6] ----
    {
        int e = tid & (TABN - 1);              // 512 threads -> 1 entry each
        float t  = ((float)e + 0.5f) * (10.0f / TABN);
        float jf = floorf(t);
        int   j0 = (int)jf;
        float u  = t - jf;
        float u2 = u * u, u3 = u2 * u;
        float Q0 = u3 * (1.0f / 6.0f);
        float d  = 1.0f - u;
        float Q3 = d * d * d * (1.0f / 6.0f);
        float Q1 = fmaf(0.5f, u + u2 - u3, 1.0f / 6.0f);
        float Q2 = fmaf(0.5f, u3, 0.66666667f - u2);
        unsigned plo = pkbf(Q3, Q2);
        unsigned phi = pkbf(Q1, Q0);
        unsigned long long P = ((unsigned long long)phi << 32) | plo;
        int sh = (j0 << 4) - 32;               // Q3 -> slot j0-2 (c = j0-3)
        unsigned a  = (unsigned)sh, na = 0u - a;
        unsigned long long lo =
            (a  < 64u) ? (P << (a  & 63u)) : ((na < 64u) ? (P >> (na & 63u)) : 0ull);
        unsigned b2 = a - 64u, nb = 0u - b2;
        unsigned long long hi =
            (b2 < 64u) ? (P << (b2 & 63u)) : ((nb < 64u) ? (P >> (nb & 63u)) : 0ull);
        lo &= ~0xFFFFull;                      // slot0 cleared (silu at use)
        uint4 w;
        w.x = (unsigned)lo; w.y = (unsigned)(lo >> 32);
        w.z = (unsigned)hi; w.w = (unsigned)(hi >> 32);
        *(uint4*)&smem[OFF_T + e * 8] = w;
    }

    // x row pointers for the 4 m-tiles this lane feeds
    const unsigned short* xrow[4];
    #pragma unroll
    for (int mt = 0; mt < 4; ++mt) {
        int row = m0 + mt * 16 + lrow;
        int eg  = e_base + row; if (eg >= NEDGES) eg = NEDGES - 1;
        xrow[mt] = Xbf + (size_t)eg * IN_DIM;
    }

    // prologue: DMA B chunks 0,1
    #pragma unroll
    for (int c = 0; c < 2; ++c)
        #pragma unroll
        for (int it = 0; it < 2; ++it) {
            int id = it * THR2 + tid;
            glds16(Wsw + (size_t)c * 8192 + id * 8, &smem[OFF_B3 + c * 8192 + id * 8]);
        }
    __syncthreads();   // table visible + B0/B1 ready (vmcnt drain)

    f32x4 acc[4][4];
    #pragma unroll
    for (int a = 0; a < 4; ++a)
        #pragma unroll
        for (int b = 0; b < 4; ++b) { f32x4 z = {0.f,0.f,0.f,0.f}; acc[a][b] = z; }

    for (int j = 0; j < 48; ++j) {             // pairs of chunks
        // x for this pair (8 scalar bf16 loads, L2/L3-resident)
        unsigned short xc[8];
        const int colb = j * 8 + lquad;
        #pragma unroll
        for (int mt = 0; mt < 4; ++mt) {
            xc[mt * 2]     = xrow[mt][colb];
            xc[mt * 2 + 1] = xrow[mt][colb + 4];
        }
        // DMA next pair into the other two buffers
        if (j < 47) {
            #pragma unroll
            for (int c = 0; c < 2; ++c) {
                int ch = 2 * j + 2 + c;
                const unsigned short* wc = Wsw + (size_t)ch * 8192;
                unsigned short* lb = &smem[OFF_B3 + (ch & 3) * 8192];
                #pragma unroll
                for (int it = 0; it < 2; ++it) {
                    int id = it * THR2 + tid;
                    glds16(wc + id * 8, lb + id * 8);
                }
            }
        }
        // process 2 chunks
        #pragma unroll
        for (int h = 0; h < 2; ++h) {
            const int ch = 2 * j + h;
            const unsigned short* bb = &smem[OFF_B3 + (ch & 3) * 8192];
            bf16x8 bfr[4];
            #pragma unroll
            for (int nt = 0; nt < 4; ++nt) {
                int n = n0 + nt * 16 + lrow;
                bfr[nt] = *(const bf16x8*)&bb[n * 32 + ((((n >> 1) + lquad) & 3) << 3)];
            }
            #pragma unroll
            for (int mt = 0; mt < 4; ++mt) {
                bf16x8 af = gen_af(xc[mt * 2 + h], hinv, b0, &smem[OFF_T]);
                #pragma unroll
                for (int nt = 0; nt < 4; ++nt)
                    acc[mt][nt] = __builtin_amdgcn_mfma_f32_16x16x32_bf16(
                        af, bfr[nt], acc[mt][nt], 0, 0, 0);
            }
        }
        __syncthreads();                        // guards B buffer recycling
    }

    // epilogue: C row = edge (m), col = out (n)
    #pragma unroll
    for (int mt = 0; mt < 4; ++mt) {
        #pragma unroll
        for (int r = 0; r < 4; ++r) {
            int row = m0 + mt * 16 + lquad * 4 + r;
            int eg  = e_base + row;
            if (eg < NEDGES) {
                float* op = out + (size_t)eg * OUT_DIM + n0 + lrow;
                #pragma unroll
                for (int nt = 0; nt < 4; ++nt)
                    op[nt * 16] = acc[mt][nt][r];
            }
        }
    }
}

// =====================================================================
// FALLBACK (no workspace): correctness-only fused kernel
// =====================================================================
#define XSTR 392
#define FSTR 72
#define FOFF_X 0
#define FOFF_A (128 * XSTR)
#define FOFF_B (FOFF_A + 128 * FSTR)
#define FLDS (FOFF_B + OUT_DIM * FSTR)

__global__ __launch_bounds__(512, 2)
void fused_fallback(const float* __restrict__ node_emb,
                    const float* __restrict__ ctx_emb,
                    const int*   __restrict__ pair,
                    const float* __restrict__ ctx_w,
                    const float* __restrict__ ctx_b,
                    const float* __restrict__ base_w,
                    const float* __restrict__ spline_w,
                    const float* __restrict__ spline_s,
                    const float* __restrict__ grid,
                    float* __restrict__ out)
{
    __shared__ unsigned short smem[FLDS];
    const int tid    = threadIdx.x;
    const int e_base = blockIdx.x * 128;
    const int wid    = tid >> 6;
    const int lan    = tid & 63;
    const int lrow   = lan & 15;
    const int lquad  = lan >> 4;

    #pragma unroll
    for (int it = 0; it < 16; ++it) {
        int id    = it * 512 + tid;
        int lane4 = id & 31;
        int e     = (id >> 5) & 127;
        int which = id >> 12;
        int eg = e_base + e; if (eg >= NEDGES) eg = NEDGES - 1;
        int node = pair[eg * 2 + which];
        const float4 v = *(const float4*)(node_emb + (size_t)node * NODE_DIM + lane4 * 4);
        *(ushort4*)&smem[FOFF_X + e * XSTR + which * NODE_DIM + lane4 * 4] =
            make_ushort4(f2bf(v.x), f2bf(v.y), f2bf(v.z), f2bf(v.w));
    }
    {
        f32x4 cacc[4][2];
        #pragma unroll
        for (int a = 0; a < 4; ++a)
            #pragma unroll
            for (int b = 0; b < 2; ++b) { f32x4 z = {0.f,0.f,0.f,0.f}; cacc[a][b] = z; }
        const int m0 = (wid & 1) * 64;
        const int n0 = (wid >> 1) * 32;
        for (int kc = 0; kc < 4; ++kc) {
            #pragma unroll
            for (int it = 0; it < 4; ++it) {
                int id = it * 512 + tid;
                int r  = id >> 4;
                int c4 = id & 15;
                int eg = e_base + r; if (eg >= NEDGES) eg = NEDGES - 1;
                float4 v = *(const float4*)(ctx_emb + (size_t)eg * CTX_DIM + kc * 64 + c4 * 4);
                *(ushort4*)&smem[FOFF_A + r * FSTR + c4 * 4] =
                    make_ushort4(f2bf(v.x), f2bf(v.y), f2bf(v.z), f2bf(v.w));
                float4 w = *(const float4*)(ctx_w + (size_t)r * CTX_DIM + kc * 64 + c4 * 4);
                *(ushort4*)&smem[FOFF_B + r * FSTR + c4 * 4] =
                    make_ushort4(f2bf(w.x), f2bf(w.y), f2bf(w.z), f2bf(w.w));
            }
            __syncthreads();
            #pragma unroll
            for (int ks = 0; ks < 2; ++ks) {
                int koff = ks * 32 + lquad * 8;
                bf16x8 af[4], bfr[2];
                #pragma unroll
                for (int mt = 0; mt < 4; ++mt)
                    af[mt] = *(const bf16x8*)&smem[FOFF_A + (m0 + mt*16 + lrow) * FSTR + koff];
                #pragma unroll
                for (int nt = 0; nt < 2; ++nt)
                    bfr[nt] = *(const bf16x8*)&smem[FOFF_B + (n0 + nt*16 + lrow) * FSTR + koff];
                #pragma unroll
                for (int mt = 0; mt < 4; ++mt)
                    #pragma unroll
                    for (int nt = 0; nt < 2; ++nt)
                        cacc[mt][nt] = __builtin_amdgcn_mfma_f32_16x16x32_bf16(
                            af[mt], bfr[nt], cacc[mt][nt], 0, 0, 0);
            }
            __syncthreads();
        }
        #pragma unroll
        for (int mt = 0; mt < 4; ++mt)
            #pragma unroll
            for (int nt = 0; nt < 2; ++nt)
                #pragma unroll
                for (int r = 0; r < 4; ++r) {
                    int row = m0 + mt*16 + lquad*4 + r;
                    int col = n0 + nt*16 + lrow;
                    smem[FOFF_X + row * XSTR + 256 + col] = f2bf(cacc[mt][nt][r] + ctx_b[col]);
                }
    }
    __syncthreads();

    const float g0   = grid[0];
    const float hinv = 1.0f / (grid[1] - grid[0]);

    f32x4 acc[4][4];
    #pragma unroll
    for (int a = 0; a < 4; ++a)
        #pragma unroll
        for (int b = 0; b < 4; ++b) { f32x4 z = {0.f,0.f,0.f,0.f}; acc[a][b] = z; }

    const int m0 = (wid & 1) * 64;
    const int n0 = (wid >> 1) * 64;

    for (int kb = 0; kb < 48; ++kb) {
        const int seg = kb / 6;
        const int i0  = (kb - seg * 6) * 64;
        #pragma unroll
        for (int it = 0; it < 4; ++it) {
            int id = it * 512 + tid;
            int e  = id >> 4;
            int qq = id & 15;
            ushort4 xv = *(const ushort4*)&smem[FOFF_X + e * XSTR + i0 + qq * 4];
            float x0 = bf2f(xv.x), x1 = bf2f(xv.y), x2 = bf2f(xv.z), x3 = bf2f(xv.w);
            unsigned short r0, r1, r2, r3;
            if (seg == 0) {
                r0 = f2bf(silu(x0)); r1 = f2bf(silu(x1));
                r2 = f2bf(silu(x2)); r3 = f2bf(silu(x3));
            } else {
                const float cf = (float)(seg - 1);
                r0 = f2bf(n3((x0 - g0) * hinv - cf));
                r1 = f2bf(n3((x1 - g0) * hinv - cf));
                r2 = f2bf(n3((x2 - g0) * hinv - cf));
                r3 = f2bf(n3((x3 - g0) * hinv - cf));
            }
            *(ushort4*)&smem[FOFF_A + e * FSTR + qq * 4] = make_ushort4(r0, r1, r2, r3);
        }
        #pragma unroll
        for (int it = 0; it < 4; ++it) {
            int id = it * 512 + tid;
            int o  = id >> 4;
            int qq = id & 15;
            unsigned short r0, r1, r2, r3;
            if (seg == 0) {
                const float4 w = *(const float4*)(base_w + (size_t)o * IN_DIM + i0 + qq * 4);
                r0 = f2bf(w.x); r1 = f2bf(w.y); r2 = f2bf(w.z); r3 = f2bf(w.w);
            } else {
                int c  = seg - 1;
                int bi = o * IN_DIM + i0 + qq * 4;
                r0 = f2bf(spline_w[(size_t)(bi    ) * NCOEF + c] * spline_s[bi    ]);
                r1 = f2bf(spline_w[(size_t)(bi + 1) * NCOEF + c] * spline_s[bi + 1]);
                r2 = f2bf(spline_w[(size_t)(bi + 2) * NCOEF + c] * spline_s[bi + 2]);
                r3 = f2bf(spline_w[(size_t)(bi + 3) * NCOEF + c] * spline_s[bi + 3]);
            }
            *(ushort4*)&smem[FOFF_B + o * FSTR + qq * 4] = make_ushort4(r0, r1, r2, r3);
        }
        __syncthreads();
        #pragma unroll
        for (int ks = 0; ks < 2; ++ks) {
            int koff = ks * 32 + lquad * 8;
            bf16x8 af[4], bfr[4];
            #pragma unroll
            for (int mt = 0; mt < 4; ++mt)
                af[mt] = *(const bf16x8*)&smem[FOFF_A + (m0 + mt*16 + lrow) * FSTR + koff];
            #pragma unroll
            for (int nt = 0; nt < 4; ++nt)
                bfr[nt] = *(const bf16x8*)&smem[FOFF_B + (n0 + nt*16 + lrow) * FSTR + koff];
            #pragma unroll
            for (int mt = 0; mt < 4; ++mt)
                #pragma unroll
                for (int nt = 0; nt < 4; ++nt)
                    acc[mt][nt] = __builtin_amdgcn_mfma_f32_16x16x32_bf16(
                        af[mt], bfr[nt], acc[mt][nt], 0, 0, 0);
        }
        __syncthreads();
    }

    #pragma unroll
    for (int mt = 0; mt < 4; ++mt) {
        #pragma unroll
        for (int r = 0; r < 4; ++r) {
            int row = m0 + mt*16 + lquad*4 + r;
            int eg  = e_base + row;
            if (eg < NEDGES) {
                float* op = out + (size_t)eg * OUT_DIM + n0 + lrow;
                #pragma unroll
                for (int nt = 0; nt < 4; ++nt)
                    op[nt * 16] = acc[mt][nt][r];
            }
        }
    }
}

// ---------------- launch ----------------
extern "C" void kernel_launch(void* const* d_in, const int* in_sizes, int n_in,
                              void* d_out, int out_size, void* d_ws, size_t ws_size,
                              hipStream_t stream)
{
    const float* node_emb = (const float*)d_in[0];
    const float* ctx_emb  = (const float*)d_in[1];
    const int*   pair     = (const int*)d_in[2];
    const float* ctx_w    = (const float*)d_in[3];
    const float* ctx_b    = (const float*)d_in[4];
    const float* base_w   = (const float*)d_in[5];
    const float* spline_w = (const float*)d_in[6];
    const float* spline_s = (const float*)d_in[7];
    const float* grid     = (const float*)d_in[8];
    float* out = (float*)d_out;

    const int nblk = (NEDGES + BM2 - 1) / BM2;     // 782
    const size_t xoff = 2u * 1024u * 1024u;
    const size_t need = xoff + (size_t)NEDGES * IN_DIM * sizeof(unsigned short);

    if (ws_size >= need) {
        unsigned short* Wsw = (unsigned short*)d_ws;
        unsigned short* Xbf = (unsigned short*)((char*)d_ws + xoff);
        prep_w2<<<OUT_DIM, IN_DIM, 0, stream>>>(base_w, spline_w, spline_s, Wsw);
        build_x<<<nblk, 512, 0, stream>>>(node_emb, ctx_emb, pair, ctx_w, ctx_b, Xbf);
        kan_gemm3<<<nblk, THR2, 0, stream>>>(Wsw, Xbf, grid, out);
    } else {
        fused_fallback<<<nblk, 512, 0, stream>>>(
            node_emb, ctx_emb, pair, ctx_w, ctx_b, base_w, spline_w, spline_s, grid, out);
    }
}